// Round 7
// baseline (365.676 us; speedup 1.0000x reference)
//
#include <hip/hip_runtime.h>
#include <hip/hip_bf16.h>

typedef __hip_bfloat16 bf16;

#define FIN 128
#define HD 256
#define NA 8

__device__ __forceinline__ float b2f(bf16 v) { return __bfloat162float(v); }
__device__ __forceinline__ float bfbits(unsigned short b) {
  unsigned v = ((unsigned)b) << 16;
  return __uint_as_float(v);
}

struct SegOffs { int o[9]; };  // 8 weight tensors; o[8] = total

// ---------------- runtime wire-dtype detection ----------------
// flags[0] = 1 if float tensors are f32 on the wire (else bf16)
// flags[1] = 1 if edge_index is int64 on the wire (else int32)
__global__ void detect_kernel(const unsigned short* xw, const int* ew, int* flags,
                              int nx_halfwords, int ne_words) {
  __shared__ int cnt0, cnt1;
  if (threadIdx.x == 0) { cnt0 = 0; cnt1 = 0; }
  __syncthreads();
  int outl = 0, zeros = 0;
  int nx = nx_halfwords < 4096 ? nx_halfwords : 4096;
  int ne = ne_words < 4096 ? ne_words : 4096;
  for (int i = threadIdx.x; i < nx; i += 256) {
    unsigned u = xw[i];
    unsigned ex = (u >> 7) & 0xFF;
    if (ex >= 134) outl++;              // |v| >= 128: impossible for N(0,1) bf16
  }
  for (int i = threadIdx.x; i < ne; i += 256) {
    if ((i & 1) && ew[i] == 0) zeros++; // high words of small int64s
  }
  atomicAdd(&cnt0, outl);
  atomicAdd(&cnt1, zeros);
  __syncthreads();
  if (threadIdx.x == 0) {
    flags[0] = (cnt0 > 100) ? 1 : 0;
    flags[1] = (cnt1 > 1000) ? 1 : 0;
  }
}

// ---------------- convert weight tensors -> contiguous f32 ----------------
__global__ void cvt_w_kernel(const void* t0, const void* t1, const void* t2,
                             const void* t3, const void* t4, const void* t5,
                             const void* t6, const void* t7,
                             SegOffs so, float* dstf, const int* flags) {
  int i = blockIdx.x * blockDim.x + threadIdx.x;
  if (i >= so.o[8]) return;
  const bool f32w = flags[0] != 0;
  const void* srcs[8] = {t0, t1, t2, t3, t4, t5, t6, t7};
  int t = 0;
  #pragma unroll
  for (int k = 1; k < 8; ++k) t += (i >= so.o[k]) ? 1 : 0;
  int off = i - so.o[t];
  const void* s = srcs[t];
  dstf[i] = f32w ? ((const float*)s)[off] : b2f(((const bf16*)s)[off]);
}

// ---------------- edges: decode + degree count (fused) ----------------
__global__ void edges_count_kernel(const int* ei, int* src, int* dst, int E,
                                   const int* flags, int* count) {
  int e = blockIdx.x * blockDim.x + threadIdx.x;
  if (e >= E) return;
  int s, d;
  if (flags[1]) { s = ei[2 * e]; d = ei[2 * (E + e)]; }
  else          { s = ei[e];     d = ei[E + e]; }
  src[e] = s;
  dst[e] = d;
  atomicAdd(&count[d], 1);
}

__global__ void dinv_kernel(const int* __restrict__ count, float* __restrict__ dinv, int n) {
  int i = blockIdx.x * blockDim.x + threadIdx.x;
  if (i < n) dinv[i] = rsqrtf((float)count[i] + 1.0f);  // +1 = self loop
}

// ---------------- parallel exclusive scan (3 phases) ----------------
__global__ void scan1_kernel(const int* count, int* offs, int* partials, int n) {
  __shared__ int lds[256];
  int tid = threadIdx.x, i = blockIdx.x * 256 + tid;
  int v = (i < n) ? count[i] : 0;
  lds[tid] = v;
  __syncthreads();
  for (int off = 1; off < 256; off <<= 1) {
    int t = (tid >= off) ? lds[tid - off] : 0;
    __syncthreads();
    lds[tid] += t;
    __syncthreads();
  }
  if (i < n) offs[i] = lds[tid] - v;       // local exclusive
  if (tid == 255) partials[blockIdx.x] = lds[255];
}

__global__ void scan2_kernel(int* partials, int* offs, int nb, int n) {
  __shared__ int lds[64];
  int tid = threadIdx.x;
  int v = (tid < nb) ? partials[tid] : 0;
  lds[tid] = v;
  __syncthreads();
  for (int off = 1; off < 64; off <<= 1) {
    int t = (tid >= off) ? lds[tid - off] : 0;
    __syncthreads();
    lds[tid] += t;
    __syncthreads();
  }
  if (tid < nb) partials[tid] = lds[tid] - v;  // exclusive over block totals
  if (tid == 63) offs[n] = lds[63];            // grand total
}

__global__ void scan3_kernel(int* offs, const int* partials, int* cursor, int n) {
  int i = blockIdx.x * 256 + threadIdx.x;
  if (i < n) {
    int o = offs[i] + partials[blockIdx.x];
    offs[i] = o;
    cursor[i] = o;
  }
}

__global__ void fill_kernel(const int* __restrict__ src, const int* __restrict__ dst,
                            const float* __restrict__ dinv, int* __restrict__ cursor,
                            int* __restrict__ csr_src, float* __restrict__ csr_w, int E) {
  int e = blockIdx.x * blockDim.x + threadIdx.x;
  if (e < E) {
    int s = src[e], d = dst[e];
    int p = atomicAdd(&cursor[d], 1);
    csr_src[p] = s;
    csr_w[p] = dinv[s] * dinv[d];
  }
}

// ---------------- agg1: gather raw x (128 feats) -> xagg f32 ----------------
// one node per wave; lane holds feats {2*lane, 2*lane+1}
__global__ void agg1_kernel(const void* __restrict__ xraw, const int* __restrict__ offs,
                            const int* __restrict__ csr_src, const float* __restrict__ csr_w,
                            const float* __restrict__ dinv, float* __restrict__ out,
                            int n, const int* flags) {
  int wave = (blockIdx.x * blockDim.x + threadIdx.x) >> 6;
  int lane = threadIdx.x & 63;
  if (wave >= n) return;
  const bool f32w = flags[0] != 0;
  const int i = wave;

  auto loadrow = [&](int s) -> float2 {
    if (f32w) return ((const float2*)xraw)[(size_t)s * 64 + lane];
    unsigned u = ((const unsigned*)xraw)[(size_t)s * 32 + lane];
    return make_float2(bfbits((unsigned short)(u & 0xFFFF)),
                       bfbits((unsigned short)(u >> 16)));
  };

  float di = dinv[i];
  float s2 = di * di;
  float2 xi = loadrow(i);
  float ax = s2 * xi.x, ay = s2 * xi.y;

  int e = offs[i], e1 = offs[i + 1];
  if (e < e1) {
    int s0 = csr_src[e];
    float w0 = csr_w[e];
    float2 r0 = loadrow(s0);
    for (++e; e < e1; ++e) {
      int s1 = csr_src[e];
      float w1 = csr_w[e];
      float2 r1 = loadrow(s1);       // in flight while consuming r0
      ax += w0 * r0.x; ay += w0 * r0.y;
      w0 = w1; r0 = r1;
    }
    ax += w0 * r0.x; ay += w0 * r0.y;
  }
  ((float2*)out)[(size_t)i * 64 + lane] = make_float2(ax, ay);
}

// ---------------- agg2: gather f32 (256 feats), fused bias+relu ----------------
// one node per wave; lane holds a float4 slice (feats 4*lane..4*lane+3)
__global__ void agg2_kernel(const float* __restrict__ tmp, const int* __restrict__ offs,
                            const int* __restrict__ csr_src, const float* __restrict__ csr_w,
                            const float* __restrict__ dinv, const float* __restrict__ bias,
                            float* __restrict__ out, int n) {
  int wave = (blockIdx.x * blockDim.x + threadIdx.x) >> 6;
  int lane = threadIdx.x & 63;
  if (wave >= n) return;
  const int i = wave;

  float di = dinv[i];
  float s2 = di * di;
  float4 xi = ((const float4*)(tmp + (size_t)i * 256))[lane];
  float4 b4 = ((const float4*)bias)[lane];
  float a0 = s2 * xi.x + b4.x, a1 = s2 * xi.y + b4.y;
  float a2 = s2 * xi.z + b4.z, a3 = s2 * xi.w + b4.w;

  int e = offs[i], e1 = offs[i + 1];
  if (e < e1) {
    int s0 = csr_src[e];
    float w0 = csr_w[e];
    float4 r0 = ((const float4*)(tmp + (size_t)s0 * 256))[lane];
    for (++e; e < e1; ++e) {
      int s1 = csr_src[e];
      float w1 = csr_w[e];
      float4 r1 = ((const float4*)(tmp + (size_t)s1 * 256))[lane];
      a0 += w0 * r0.x; a1 += w0 * r0.y; a2 += w0 * r0.z; a3 += w0 * r0.w;
      w0 = w1; r0 = r1;
    }
    a0 += w0 * r0.x; a1 += w0 * r0.y; a2 += w0 * r0.z; a3 += w0 * r0.w;
  }
  float4 res = make_float4(fmaxf(a0, 0.f), fmaxf(a1, 0.f), fmaxf(a2, 0.f), fmaxf(a3, 0.f));
  ((float4*)(out + (size_t)i * 256))[lane] = res;
}

// ---------------- GEMM: [N x K] @ [K x 256] -> f32 [N x 256] ----------------
// 16 rows/block, 256 threads. B staged through LDS in K-chunks of 16,
// double-buffered with register prefetch. Thread tile: 4 rows x 4 scattered
// cols {c, c+64, c+128, c+192} -> B LDS reads 2-way/bank (free), A reads
// wave-uniform broadcast. One barrier per chunk.
template<int K, bool BIAS, bool RELU>
__global__ __launch_bounds__(256, 3)
void gemm256(const float* __restrict__ A, const float* __restrict__ B,
             const float* __restrict__ bias, float* __restrict__ C, int N) {
  constexpr int KC = 16;
  constexpr int NCH = K / KC;
  __shared__ float a_lds[16 * K];
  __shared__ float b_lds[2][KC * 256];
  const int tid = threadIdx.x;
  const int row0 = blockIdx.x * 16;

  // stage A: 16 rows x K (float4 coalesced)
  for (int idx = tid; idx < 16 * (K / 4); idx += 256) {
    int r = idx / (K / 4);
    int k4 = idx - r * (K / 4);
    int gr = row0 + r;
    float4 v = make_float4(0.f, 0.f, 0.f, 0.f);
    if (gr < N) v = ((const float4*)A)[(size_t)gr * (K / 4) + k4];
    ((float4*)a_lds)[idx] = v;
  }

  // prefetch + stage B chunk 0 (chunk = KC*256 floats = 1024 float4)
  const float4* Bv = (const float4*)B;
  float4 pre[4];
  #pragma unroll
  for (int i = 0; i < 4; ++i) pre[i] = Bv[tid + i * 256];
  #pragma unroll
  for (int i = 0; i < 4; ++i) ((float4*)b_lds[0])[tid + i * 256] = pre[i];

  const int c  = tid & 63;          // base col
  const int r0 = (tid >> 6) * 4;    // wave-uniform row quad
  float acc[4][4] = {};

  for (int ch = 0; ch < NCH; ++ch) {
    if (ch + 1 < NCH) {             // issue next-chunk loads early (in flight
      size_t base = (size_t)(ch + 1) * (KC * 64);   //  across barrier+compute)
      #pragma unroll
      for (int i = 0; i < 4; ++i) pre[i] = Bv[base + tid + i * 256];
    }
    __syncthreads();                // buf[ch&1] (and A on ch==0) ready
    const float* bl = b_lds[ch & 1];
    const float* al = a_lds + ch * KC;
    #pragma unroll
    for (int kk = 0; kk < KC; ++kk) {
      float b0 = bl[kk * 256 + c];
      float b1 = bl[kk * 256 + c + 64];
      float b2 = bl[kk * 256 + c + 128];
      float b3 = bl[kk * 256 + c + 192];
      #pragma unroll
      for (int r = 0; r < 4; ++r) {
        float a = al[(r0 + r) * K + kk];
        acc[r][0] += a * b0;
        acc[r][1] += a * b1;
        acc[r][2] += a * b2;
        acc[r][3] += a * b3;
      }
    }
    if (ch + 1 < NCH) {
      // safe without extra barrier: top-of-chunk rendezvous guarantees no
      // wave still reads buf[(ch+1)&1] (last read in chunk ch-1)
      #pragma unroll
      for (int i = 0; i < 4; ++i) ((float4*)b_lds[(ch + 1) & 1])[tid + i * 256] = pre[i];
    }
  }

  float bb[4] = {0.f, 0.f, 0.f, 0.f};
  if (BIAS) {
    #pragma unroll
    for (int j = 0; j < 4; ++j) bb[j] = bias[c + 64 * j];
  }
  #pragma unroll
  for (int r = 0; r < 4; ++r) {
    int gr = row0 + r0 + r;
    if (gr < N) {
      #pragma unroll
      for (int j = 0; j < 4; ++j) {
        float v = acc[r][j] + bb[j];
        if (RELU) v = fmaxf(v, 0.f);
        C[(size_t)gr * 256 + c + 64 * j] = v;
      }
    }
  }
}

// ---------------- final projection: [N x 256] @ [256 x 8] + b ---------------
__global__ void gemm_out_kernel(const float* __restrict__ A, const float* __restrict__ B,
                                const float* __restrict__ bias, void* __restrict__ out,
                                int N, const int* flags) {
  __shared__ float w[HD * NA];
  __shared__ float bs[NA];
  const int tid = threadIdx.x;
  for (int idx = tid; idx < HD * NA; idx += 256) w[idx] = B[idx];
  if (tid < NA) bs[tid] = bias[tid];
  __syncthreads();
  int row = blockIdx.x * 32 + (tid >> 3);
  int j = tid & 7;
  if (row < N) {
    float acc = 0.f;
    #pragma unroll 4
    for (int k = 0; k < HD; ++k) acc += A[(size_t)row * HD + k] * w[k * NA + j];
    float v = acc + bs[j];
    if (flags[0]) ((float*)out)[(size_t)row * NA + j] = v;
    else          ((bf16*)out)[(size_t)row * NA + j] = __float2bfloat16(v);
  }
}

// ---------------- launch ----------------
extern "C" void kernel_launch(void* const* d_in, const int* in_sizes, int n_in,
                              void* d_out, int out_size, void* d_ws, size_t ws_size,
                              hipStream_t stream) {
  (void)n_in; (void)out_size; (void)ws_size;
  const void* x_raw  = d_in[0];
  const int*  ei_raw = (const int*)d_in[1];

  const int N = in_sizes[0] / FIN;
  const int E = in_sizes[1] / 2;

  // weight-tensor segment offsets (inputs 2..9)
  SegOffs so;
  int acc = 0;
  for (int t = 0; t < 8; ++t) { so.o[t] = acc; acc += in_sizes[t + 2]; }
  so.o[8] = acc;

  char* ws = (char*)d_ws;
  size_t off = 0;
  auto walloc = [&](size_t bytes) -> void* {
    void* p = ws + off;
    off = (off + bytes + 255) & ~(size_t)255;
    return p;
  };
  float* wf      = (float*)walloc((size_t)acc * 4);
  int*   flags   = (int*)walloc(16);
  float* dinv    = (float*)walloc((size_t)N * 4);
  int*   count   = (int*)walloc((size_t)N * 4);
  int*   offs    = (int*)walloc((size_t)(N + 1) * 4);
  int*   cursor  = (int*)walloc((size_t)N * 4);
  int*   partials= (int*)walloc(64 * 4);
  int*   csr_src = (int*)walloc((size_t)E * 4);
  float* csr_w   = (float*)walloc((size_t)E * 4);
  int*   src32   = (int*)walloc((size_t)E * 4);
  int*   dst32   = (int*)walloc((size_t)E * 4);
  float* xagg    = (float*)walloc((size_t)N * FIN * 4);
  float* bufA    = (float*)walloc((size_t)N * HD * 4);
  float* bufB    = (float*)walloc((size_t)N * HD * 4);

  const float* w1f  = wf + so.o[0];
  const float* b1f  = wf + so.o[1];
  const float* w2f  = wf + so.o[2];
  const float* b2f  = wf + so.o[3];
  const float* wh1f = wf + so.o[4];
  const float* bh1f = wf + so.o[5];
  const float* wh2f = wf + so.o[6];
  const float* bh2f = wf + so.o[7];

  detect_kernel<<<1, 256, 0, stream>>>((const unsigned short*)x_raw, ei_raw, flags,
                                       in_sizes[0], in_sizes[1]);

  cvt_w_kernel<<<(acc + 255) / 256, 256, 0, stream>>>(
      d_in[2], d_in[3], d_in[4], d_in[5], d_in[6], d_in[7], d_in[8], d_in[9],
      so, wf, flags);

  hipMemsetAsync(count, 0, (size_t)N * 4, stream);

  const int eb = 256;
  const int eg = (E + eb - 1) / eb;
  edges_count_kernel<<<eg, eb, 0, stream>>>(ei_raw, src32, dst32, E, flags, count);
  dinv_kernel<<<(N + 255) / 256, 256, 0, stream>>>(count, dinv, N);

  const int nb = (N + 255) / 256;
  scan1_kernel<<<nb, 256, 0, stream>>>(count, offs, partials, N);
  scan2_kernel<<<1, 64, 0, stream>>>(partials, offs, nb, N);
  scan3_kernel<<<nb, 256, 0, stream>>>(offs, partials, cursor, N);

  fill_kernel<<<eg, eb, 0, stream>>>(src32, dst32, dinv, cursor, csr_src, csr_w, E);

  const int ab = (N + 3) / 4;  // 4 waves (nodes) per block
  // conv1 (reassociated): xagg = Ahat @ x ; bufA = relu(xagg @ W1 + b1)
  agg1_kernel<<<ab, 256, 0, stream>>>(x_raw, offs, csr_src, csr_w, dinv, xagg, N, flags);
  gemm256<FIN, true,  true ><<<(N + 15) / 16, 256, 0, stream>>>(xagg, w1f, b1f, bufA, N);
  // conv2: bufB = bufA @ W2 ; bufA = relu(Ahat @ bufB + b2)
  gemm256<HD,  false, false><<<(N + 15) / 16, 256, 0, stream>>>(bufA, w2f, nullptr, bufB, N);
  agg2_kernel<<<ab, 256, 0, stream>>>(bufB, offs, csr_src, csr_w, dinv, b2f, bufA, N);
  // dense: bufB = relu(bufA @ Wh1 + bh1)
  gemm256<HD,  true,  true ><<<(N + 15) / 16, 256, 0, stream>>>(bufA, wh1f, bh1f, bufB, N);
  // out = bufB @ Wh2 + bh2
  gemm_out_kernel<<<(N + 31) / 32, 256, 0, stream>>>(bufB, wh2f, bh2f, d_out, N, flags);
}

// Round 8
// 295.369 us; speedup vs baseline: 1.2380x; 1.2380x over previous
//
#include <hip/hip_runtime.h>
#include <hip/hip_bf16.h>

typedef __hip_bfloat16 bf16;

#define FIN 128
#define HD 256
#define NA 8

__device__ __forceinline__ float b2f(bf16 v) { return __bfloat162float(v); }
__device__ __forceinline__ float bfbits(unsigned short b) {
  unsigned v = ((unsigned)b) << 16;
  return __uint_as_float(v);
}

struct SegOffs { int o[9]; };  // 8 weight tensors; o[8] = total

// ---------------- runtime wire-dtype detection ----------------
// flags[0] = 1 if float tensors are f32 on the wire (else bf16)
// flags[1] = 1 if edge_index is int64 on the wire (else int32)
__global__ void detect_kernel(const unsigned short* xw, const int* ew, int* flags,
                              int nx_halfwords, int ne_words) {
  __shared__ int cnt0, cnt1;
  if (threadIdx.x == 0) { cnt0 = 0; cnt1 = 0; }
  __syncthreads();
  int outl = 0, zeros = 0;
  int nx = nx_halfwords < 4096 ? nx_halfwords : 4096;
  int ne = ne_words < 4096 ? ne_words : 4096;
  for (int i = threadIdx.x; i < nx; i += 256) {
    unsigned u = xw[i];
    unsigned ex = (u >> 7) & 0xFF;
    if (ex >= 134) outl++;              // |v| >= 128: impossible for N(0,1) bf16
  }
  for (int i = threadIdx.x; i < ne; i += 256) {
    if ((i & 1) && ew[i] == 0) zeros++; // high words of small int64s
  }
  atomicAdd(&cnt0, outl);
  atomicAdd(&cnt1, zeros);
  __syncthreads();
  if (threadIdx.x == 0) {
    flags[0] = (cnt0 > 100) ? 1 : 0;
    flags[1] = (cnt1 > 1000) ? 1 : 0;
  }
}

// ------- convert weight tensors -> contiguous f32; also zero count[] -------
__global__ void cvt_w_kernel(const void* t0, const void* t1, const void* t2,
                             const void* t3, const void* t4, const void* t5,
                             const void* t6, const void* t7,
                             SegOffs so, float* dstf, const int* flags,
                             int* count, int ncount) {
  int i = blockIdx.x * blockDim.x + threadIdx.x;
  if (i < ncount) count[i] = 0;
  if (i >= so.o[8]) return;
  const bool f32w = flags[0] != 0;
  const void* srcs[8] = {t0, t1, t2, t3, t4, t5, t6, t7};
  int t = 0;
  #pragma unroll
  for (int k = 1; k < 8; ++k) t += (i >= so.o[k]) ? 1 : 0;
  int off = i - so.o[t];
  const void* s = srcs[t];
  dstf[i] = f32w ? ((const float*)s)[off] : b2f(((const bf16*)s)[off]);
}

// ---------------- edges: decode + degree count (fused) ----------------
__global__ void edges_count_kernel(const int* ei, int* src, int* dst, int E,
                                   const int* flags, int* count) {
  int e = blockIdx.x * blockDim.x + threadIdx.x;
  if (e >= E) return;
  int s, d;
  if (flags[1]) { s = ei[2 * e]; d = ei[2 * (E + e)]; }
  else          { s = ei[e];     d = ei[E + e]; }
  src[e] = s;
  dst[e] = d;
  atomicAdd(&count[d], 1);
}

// ------- parallel exclusive scan (3 phases); scan1 also computes dinv -------
__global__ void scan1_kernel(const int* count, int* offs, int* partials,
                             float* dinv, int n) {
  __shared__ int lds[256];
  int tid = threadIdx.x, i = blockIdx.x * 256 + tid;
  int v = (i < n) ? count[i] : 0;
  if (i < n) dinv[i] = rsqrtf((float)v + 1.0f);  // +1 = self loop
  lds[tid] = v;
  __syncthreads();
  for (int off = 1; off < 256; off <<= 1) {
    int t = (tid >= off) ? lds[tid - off] : 0;
    __syncthreads();
    lds[tid] += t;
    __syncthreads();
  }
  if (i < n) offs[i] = lds[tid] - v;       // local exclusive
  if (tid == 255) partials[blockIdx.x] = lds[255];
}

__global__ void scan2_kernel(int* partials, int* offs, int nb, int n) {
  __shared__ int lds[64];
  int tid = threadIdx.x;
  int v = (tid < nb) ? partials[tid] : 0;
  lds[tid] = v;
  __syncthreads();
  for (int off = 1; off < 64; off <<= 1) {
    int t = (tid >= off) ? lds[tid - off] : 0;
    __syncthreads();
    lds[tid] += t;
    __syncthreads();
  }
  if (tid < nb) partials[tid] = lds[tid] - v;  // exclusive over block totals
  if (tid == 63) offs[n] = lds[63];            // grand total
}

__global__ void scan3_kernel(int* offs, const int* partials, int* cursor, int n) {
  int i = blockIdx.x * 256 + threadIdx.x;
  if (i < n) {
    int o = offs[i] + partials[blockIdx.x];
    offs[i] = o;
    cursor[i] = o;
  }
}

__global__ void fill_kernel(const int* __restrict__ src, const int* __restrict__ dst,
                            const float* __restrict__ dinv, int* __restrict__ cursor,
                            int* __restrict__ csr_src, float* __restrict__ csr_w, int E) {
  int e = blockIdx.x * blockDim.x + threadIdx.x;
  if (e < E) {
    int s = src[e], d = dst[e];
    int p = atomicAdd(&cursor[d], 1);
    csr_src[p] = s;
    csr_w[p] = dinv[s] * dinv[d];
  }
}

// ---------------- agg1: gather raw x (128 feats) -> xagg f32 ----------------
__global__ void agg1_kernel(const void* __restrict__ xraw, const int* __restrict__ offs,
                            const int* __restrict__ csr_src, const float* __restrict__ csr_w,
                            const float* __restrict__ dinv, float* __restrict__ out,
                            int n, const int* flags) {
  int wave = (blockIdx.x * blockDim.x + threadIdx.x) >> 6;
  int lane = threadIdx.x & 63;
  if (wave >= n) return;
  const bool f32w = flags[0] != 0;
  const int i = wave;

  auto loadrow = [&](int s) -> float2 {
    if (f32w) return ((const float2*)xraw)[(size_t)s * 64 + lane];
    unsigned u = ((const unsigned*)xraw)[(size_t)s * 32 + lane];
    return make_float2(bfbits((unsigned short)(u & 0xFFFF)),
                       bfbits((unsigned short)(u >> 16)));
  };

  float di = dinv[i];
  float s2 = di * di;
  float2 xi = loadrow(i);
  float ax = s2 * xi.x, ay = s2 * xi.y;

  int e = offs[i], e1 = offs[i + 1];
  if (e < e1) {
    int s0 = csr_src[e];
    float w0 = csr_w[e];
    float2 r0 = loadrow(s0);
    for (++e; e < e1; ++e) {
      int s1 = csr_src[e];
      float w1 = csr_w[e];
      float2 r1 = loadrow(s1);       // in flight while consuming r0
      ax += w0 * r0.x; ay += w0 * r0.y;
      w0 = w1; r0 = r1;
    }
    ax += w0 * r0.x; ay += w0 * r0.y;
  }
  ((float2*)out)[(size_t)i * 64 + lane] = make_float2(ax, ay);
}

// ------------ agg2: gather f32 (256 feats), fused bias+relu ------------
__global__ void agg2_kernel(const float* __restrict__ tmp, const int* __restrict__ offs,
                            const int* __restrict__ csr_src, const float* __restrict__ csr_w,
                            const float* __restrict__ dinv, const float* __restrict__ bias,
                            float* __restrict__ out, int n) {
  int wave = (blockIdx.x * blockDim.x + threadIdx.x) >> 6;
  int lane = threadIdx.x & 63;
  if (wave >= n) return;
  const int i = wave;

  float di = dinv[i];
  float s2 = di * di;
  float4 xi = ((const float4*)(tmp + (size_t)i * 256))[lane];
  float4 b4 = ((const float4*)bias)[lane];
  float a0 = s2 * xi.x + b4.x, a1 = s2 * xi.y + b4.y;
  float a2 = s2 * xi.z + b4.z, a3 = s2 * xi.w + b4.w;

  int e = offs[i], e1 = offs[i + 1];
  if (e < e1) {
    int s0 = csr_src[e];
    float w0 = csr_w[e];
    float4 r0 = ((const float4*)(tmp + (size_t)s0 * 256))[lane];
    for (++e; e < e1; ++e) {
      int s1 = csr_src[e];
      float w1 = csr_w[e];
      float4 r1 = ((const float4*)(tmp + (size_t)s1 * 256))[lane];
      a0 += w0 * r0.x; a1 += w0 * r0.y; a2 += w0 * r0.z; a3 += w0 * r0.w;
      w0 = w1; r0 = r1;
    }
    a0 += w0 * r0.x; a1 += w0 * r0.y; a2 += w0 * r0.z; a3 += w0 * r0.w;
  }
  float4 res = make_float4(fmaxf(a0, 0.f), fmaxf(a1, 0.f), fmaxf(a2, 0.f), fmaxf(a3, 0.f));
  ((float4*)(out + (size_t)i * 256))[lane] = res;
}

// ---------------- GEMM: [N x K] @ [K x 256] -> f32 [N x 256] ----------------
// 16 rows/block, 256 threads. A staged in LDS (wave-uniform b128 broadcast
// reads); B streamed from L2 through a depth-4 rotating float4 register
// pipeline (4 loads in flight while 4 consumed). Thread tile 4 rows x 4
// contiguous cols -> coalesced float4 C writes.
// FUSE_OUT: instead of writing C, apply bias+relu and compute the final
// [256 x 8] projection in-register via per-lane partials + wave shfl-reduce.
template<int K, bool BIAS, bool RELU, bool FUSE_OUT>
__global__ __launch_bounds__(256, 3)
void gemm256(const float* __restrict__ A, const float* __restrict__ B,
             const float* __restrict__ bias, float* __restrict__ C, int N,
             const float* __restrict__ Wout, const float* __restrict__ bout,
             void* __restrict__ qout, const int* __restrict__ flags) {
  __shared__ float a_lds[16 * K];
  const int tid = threadIdx.x;
  const int row0 = blockIdx.x * 16;

  // stage A: 16 rows x K (float4 coalesced)
  for (int idx = tid; idx < 16 * (K / 4); idx += 256) {
    int r = idx / (K / 4);
    int k4 = idx - r * (K / 4);
    int gr = row0 + r;
    float4 v = make_float4(0.f, 0.f, 0.f, 0.f);
    if (gr < N) v = ((const float4*)A)[(size_t)gr * (K / 4) + k4];
    ((float4*)a_lds)[idx] = v;
  }
  __syncthreads();

  const int bcol = tid & 63;         // float4 column index (cols 4*bcol..+3)
  const int jq   = bcol * 4;
  const int r0   = (tid >> 6) * 4;   // wave-uniform row quad
  const float4* Bv = (const float4*)B;   // row k at Bv[k*64 + bcol]

  float acc[4][4] = {};
  float4 bv[4];
  #pragma unroll
  for (int p = 0; p < 4; ++p) bv[p] = Bv[p * 64 + bcol];

  for (int k0 = 0; k0 < K; k0 += 4) {
    float4 cur[4];
    #pragma unroll
    for (int p = 0; p < 4; ++p) cur[p] = bv[p];
    if (k0 + 4 < K) {
      #pragma unroll
      for (int p = 0; p < 4; ++p) bv[p] = Bv[(k0 + 4 + p) * 64 + bcol];
    }
    #pragma unroll
    for (int r = 0; r < 4; ++r) {
      const float4 a4 = *reinterpret_cast<const float4*>(&a_lds[(r0 + r) * K + k0]);
      acc[r][0] += a4.x * cur[0].x; acc[r][1] += a4.x * cur[0].y;
      acc[r][2] += a4.x * cur[0].z; acc[r][3] += a4.x * cur[0].w;
      acc[r][0] += a4.y * cur[1].x; acc[r][1] += a4.y * cur[1].y;
      acc[r][2] += a4.y * cur[1].z; acc[r][3] += a4.y * cur[1].w;
      acc[r][0] += a4.z * cur[2].x; acc[r][1] += a4.z * cur[2].y;
      acc[r][2] += a4.z * cur[2].z; acc[r][3] += a4.z * cur[2].w;
      acc[r][0] += a4.w * cur[3].x; acc[r][1] += a4.w * cur[3].y;
      acc[r][2] += a4.w * cur[3].z; acc[r][3] += a4.w * cur[3].w;
    }
  }

  float bb[4] = {0.f, 0.f, 0.f, 0.f};
  if (BIAS) {
    #pragma unroll
    for (int j = 0; j < 4; ++j) bb[j] = bias[jq + j];
  }
  #pragma unroll
  for (int r = 0; r < 4; ++r) {
    #pragma unroll
    for (int j = 0; j < 4; ++j) {
      acc[r][j] += bb[j];
      if (RELU) acc[r][j] = fmaxf(acc[r][j], 0.f);
    }
  }

  if constexpr (!FUSE_OUT) {
    #pragma unroll
    for (int r = 0; r < 4; ++r) {
      int gr = row0 + r0 + r;
      if (gr < N) {
        *reinterpret_cast<float4*>(&C[(size_t)gr * 256 + jq]) =
            make_float4(acc[r][0], acc[r][1], acc[r][2], acc[r][3]);
      }
    }
  } else {
    // fused projection: q[row][j] = sum_k h[row][k] * Wout[k][j] + bout[j]
    // lane holds h[row][4*bcol .. +3]; load Wout rows 4*bcol..+3 (8 cols)
    const int lane = tid & 63;
    const float4* Wv = (const float4*)Wout;   // Wout row k: Wv[k*2], Wv[k*2+1]
    float4 w0[4], w1[4];
    #pragma unroll
    for (int i = 0; i < 4; ++i) {
      w0[i] = Wv[(size_t)(jq + i) * 2];
      w1[i] = Wv[(size_t)(jq + i) * 2 + 1];
    }
    float p[4][8];
    #pragma unroll
    for (int r = 0; r < 4; ++r) {
      p[r][0] = acc[r][0]*w0[0].x + acc[r][1]*w0[1].x + acc[r][2]*w0[2].x + acc[r][3]*w0[3].x;
      p[r][1] = acc[r][0]*w0[0].y + acc[r][1]*w0[1].y + acc[r][2]*w0[2].y + acc[r][3]*w0[3].y;
      p[r][2] = acc[r][0]*w0[0].z + acc[r][1]*w0[1].z + acc[r][2]*w0[2].z + acc[r][3]*w0[3].z;
      p[r][3] = acc[r][0]*w0[0].w + acc[r][1]*w0[1].w + acc[r][2]*w0[2].w + acc[r][3]*w0[3].w;
      p[r][4] = acc[r][0]*w1[0].x + acc[r][1]*w1[1].x + acc[r][2]*w1[2].x + acc[r][3]*w1[3].x;
      p[r][5] = acc[r][0]*w1[0].y + acc[r][1]*w1[1].y + acc[r][2]*w1[2].y + acc[r][3]*w1[3].y;
      p[r][6] = acc[r][0]*w1[0].z + acc[r][1]*w1[1].z + acc[r][2]*w1[2].z + acc[r][3]*w1[3].z;
      p[r][7] = acc[r][0]*w1[0].w + acc[r][1]*w1[1].w + acc[r][2]*w1[2].w + acc[r][3]*w1[3].w;
    }
    #pragma unroll
    for (int r = 0; r < 4; ++r) {
      #pragma unroll
      for (int j = 0; j < 8; ++j) {
        float s = p[r][j];
        s += __shfl_xor(s, 1);  s += __shfl_xor(s, 2);  s += __shfl_xor(s, 4);
        s += __shfl_xor(s, 8);  s += __shfl_xor(s, 16); s += __shfl_xor(s, 32);
        p[r][j] = s;
      }
    }
    if (lane < 32) {
      const int rsel = lane >> 3, jsel = lane & 7;
      // compile-time-indexed select (avoid runtime-indexed register array)
      float res = 0.f;
      #pragma unroll
      for (int r = 0; r < 4; ++r)
        #pragma unroll
        for (int j = 0; j < 8; ++j)
          if (rsel == r && jsel == j) res = p[r][j];
      int gr = row0 + r0 + rsel;
      if (gr < N) {
        float v = res + bout[jsel];
        if (flags[0]) ((float*)qout)[(size_t)gr * NA + jsel] = v;
        else          ((bf16*)qout)[(size_t)gr * NA + jsel] = __float2bfloat16(v);
      }
    }
  }
}

// ---------------- launch ----------------
extern "C" void kernel_launch(void* const* d_in, const int* in_sizes, int n_in,
                              void* d_out, int out_size, void* d_ws, size_t ws_size,
                              hipStream_t stream) {
  (void)n_in; (void)out_size; (void)ws_size;
  const void* x_raw  = d_in[0];
  const int*  ei_raw = (const int*)d_in[1];

  const int N = in_sizes[0] / FIN;
  const int E = in_sizes[1] / 2;

  // weight-tensor segment offsets (inputs 2..9)
  SegOffs so;
  int acc = 0;
  for (int t = 0; t < 8; ++t) { so.o[t] = acc; acc += in_sizes[t + 2]; }
  so.o[8] = acc;

  char* ws = (char*)d_ws;
  size_t off = 0;
  auto walloc = [&](size_t bytes) -> void* {
    void* p = ws + off;
    off = (off + bytes + 255) & ~(size_t)255;
    return p;
  };
  float* wf      = (float*)walloc((size_t)acc * 4);
  int*   flags   = (int*)walloc(16);
  float* dinv    = (float*)walloc((size_t)N * 4);
  int*   count   = (int*)walloc((size_t)N * 4);
  int*   offs    = (int*)walloc((size_t)(N + 1) * 4);
  int*   cursor  = (int*)walloc((size_t)N * 4);
  int*   partials= (int*)walloc(64 * 4);
  int*   csr_src = (int*)walloc((size_t)E * 4);
  float* csr_w   = (float*)walloc((size_t)E * 4);
  int*   src32   = (int*)walloc((size_t)E * 4);
  int*   dst32   = (int*)walloc((size_t)E * 4);
  float* xagg    = (float*)walloc((size_t)N * FIN * 4);
  float* bufA    = (float*)walloc((size_t)N * HD * 4);
  float* bufB    = (float*)walloc((size_t)N * HD * 4);

  const float* w1f  = wf + so.o[0];
  const float* b1f  = wf + so.o[1];
  const float* w2f  = wf + so.o[2];
  const float* b2f  = wf + so.o[3];
  const float* wh1f = wf + so.o[4];
  const float* bh1f = wf + so.o[5];
  const float* wh2f = wf + so.o[6];
  const float* bh2f = wf + so.o[7];

  detect_kernel<<<1, 256, 0, stream>>>((const unsigned short*)x_raw, ei_raw, flags,
                                       in_sizes[0], in_sizes[1]);

  cvt_w_kernel<<<(acc + 255) / 256, 256, 0, stream>>>(
      d_in[2], d_in[3], d_in[4], d_in[5], d_in[6], d_in[7], d_in[8], d_in[9],
      so, wf, flags, count, N);

  const int eb = 256;
  const int eg = (E + eb - 1) / eb;
  edges_count_kernel<<<eg, eb, 0, stream>>>(ei_raw, src32, dst32, E, flags, count);

  const int nb = (N + 255) / 256;
  scan1_kernel<<<nb, 256, 0, stream>>>(count, offs, partials, dinv, N);
  scan2_kernel<<<1, 64, 0, stream>>>(partials, offs, nb, N);
  scan3_kernel<<<nb, 256, 0, stream>>>(offs, partials, cursor, N);

  fill_kernel<<<eg, eb, 0, stream>>>(src32, dst32, dinv, cursor, csr_src, csr_w, E);

  const int ab = (N + 3) / 4;        // 4 waves (nodes) per block
  const int gb = (N + 15) / 16;      // gemm blocks
  // conv1 (reassociated): xagg = Ahat @ x ; bufA = relu(xagg @ W1 + b1)
  agg1_kernel<<<ab, 256, 0, stream>>>(x_raw, offs, csr_src, csr_w, dinv, xagg, N, flags);
  gemm256<FIN, true,  true,  false><<<gb, 256, 0, stream>>>(
      xagg, w1f, b1f, bufA, N, nullptr, nullptr, nullptr, flags);
  // conv2: bufB = bufA @ W2 ; bufA = relu(Ahat @ bufB + b2)
  gemm256<HD,  false, false, false><<<gb, 256, 0, stream>>>(
      bufA, w2f, nullptr, bufB, N, nullptr, nullptr, nullptr, flags);
  agg2_kernel<<<ab, 256, 0, stream>>>(bufB, offs, csr_src, csr_w, dinv, b2f, bufA, N);
  // dense + fused projection: q = relu(bufA @ Wh1 + bh1) @ Wh2 + bh2
  gemm256<HD,  true,  true,  true ><<<gb, 256, 0, stream>>>(
      bufA, wh1f, bh1f, bufB, N, wh2f, bh2f, d_out, flags);
}